// Round 2
// baseline (1354.860 us; speedup 1.0000x reference)
//
#include <hip/hip_runtime.h>
#include <stdint.h>

#define KVOL 27
#define CIN  32
#define COUT 64
#define KPG  3          // kernel offsets per wave-group
#define NGRP 9          // KVOL / KPG waves per block
#define RB   64         // output rows per block (N % RB == 0 for N=200000)
#define SCAN_CHUNK 4096 // 256 threads * 16 elements

// ---------------------------------------------------------------------------
// 1) histogram: count[kgroup*N + out] over all K*M pairs
// ---------------------------------------------------------------------------
__global__ __launch_bounds__(256) void hist_kernel(const int2* __restrict__ kmap,
                                                   int* __restrict__ count,
                                                   int M, int N) {
  int m = blockIdx.x * 256 + threadIdx.x;
  int k = blockIdx.y;
  if (m < M) {
    int out = kmap[(size_t)k * M + m].y;
    int w = k / KPG;
    atomicAdd(&count[w * N + out], 1);
  }
}

// ---------------------------------------------------------------------------
// 2a) per-chunk reduce: partial[blk] = sum of count[blk*4096 .. +4096)
// ---------------------------------------------------------------------------
__global__ __launch_bounds__(256) void scan_reduce(const int* __restrict__ count,
                                                   int* __restrict__ partial, int nb) {
  __shared__ int ws[4];
  int t = threadIdx.x;
  int base = blockIdx.x * SCAN_CHUNK + t * 16;
  int s = 0;
#pragma unroll
  for (int i = 0; i < 16; ++i) { int idx = base + i; if (idx < nb) s += count[idx]; }
  for (int d = 32; d; d >>= 1) s += __shfl_down(s, d);
  if ((t & 63) == 0) ws[t >> 6] = s;
  __syncthreads();
  if (t == 0) partial[blockIdx.x] = ws[0] + ws[1] + ws[2] + ws[3];
}

// ---------------------------------------------------------------------------
// 2b) single-wave exclusive scan of partials (in place); also start[nb] = total
// ---------------------------------------------------------------------------
__global__ __launch_bounds__(64) void scan_partials(int* __restrict__ partial,
                                                    int nchunks, int* __restrict__ start_nb) {
  int lane = threadIdx.x;
  int run = 0;
  for (int base = 0; base < nchunks; base += 64) {
    int i = base + lane;
    int orig = (i < nchunks) ? partial[i] : 0;
    int v = orig;
    for (int d = 1; d < 64; d <<= 1) { int u = __shfl_up(v, d); if (lane >= d) v += u; }
    if (i < nchunks) partial[i] = run + v - orig;   // exclusive
    run += __shfl(v, 63);
  }
  if (lane == 0) *start_nb = run;                   // total = E
}

// ---------------------------------------------------------------------------
// 2c) downsweep: start[i] = cursor[i] = exclusive scan of count, + chunk base
// ---------------------------------------------------------------------------
__global__ __launch_bounds__(256) void scan_down(const int* __restrict__ count,
                                                 const int* __restrict__ partial,
                                                 int* __restrict__ start,
                                                 int* __restrict__ cursor, int nb) {
  __shared__ int wsum[4];
  int t = threadIdx.x, blk = blockIdx.x;
  int base = blk * SCAN_CHUNK + t * 16;
  int v[16]; int s = 0;
#pragma unroll
  for (int i = 0; i < 16; ++i) { int idx = base + i; v[i] = (idx < nb) ? count[idx] : 0; s += v[i]; }
  int lane = t & 63, wv = t >> 6;
  int sv = s;
  for (int d = 1; d < 64; d <<= 1) { int u = __shfl_up(sv, d); if (lane >= d) sv += u; }
  if (lane == 63) wsum[wv] = sv;
  __syncthreads();
  int wbase = 0;
  for (int i = 0; i < wv; ++i) wbase += wsum[i];
  int prefix = partial[blk] + wbase + (sv - s);     // exclusive prefix for this thread
#pragma unroll
  for (int i = 0; i < 16; ++i) {
    int idx = base + i;
    if (idx < nb) { start[idx] = prefix; cursor[idx] = prefix; }
    prefix += v[i];
  }
}

// ---------------------------------------------------------------------------
// 3) scatter pairs into bins: binned[pos] = in | klocal<<18 | (out%RB)<<20
// ---------------------------------------------------------------------------
__global__ __launch_bounds__(256) void scatter_kernel(const int2* __restrict__ kmap,
                                                      int* __restrict__ cursor,
                                                      uint32_t* __restrict__ binned,
                                                      int M, int N) {
  int m = blockIdx.x * 256 + threadIdx.x;
  int k = blockIdx.y;
  if (m < M) {
    int2 p = kmap[(size_t)k * M + m];
    int w = k / KPG, kl = k - w * KPG;
    int pos = atomicAdd(&cursor[w * N + p.y], 1);
    binned[pos] = (uint32_t)p.x | ((uint32_t)kl << 18) | ((uint32_t)(p.y & (RB - 1)) << 20);
  }
}

// ---------------------------------------------------------------------------
// 4) main: block = NGRP waves, 64 rows. Wave w holds 3 offsets' weights in
//    VGPRs, walks bins [w*N+R0, w*N+R0+RB), accumulates into LDS tile via
//    ds_add_f32; block writes tile + bias once (rows disjoint -> no atomics).
// ---------------------------------------------------------------------------
#define DOT32(F, W, ACC) { _Pragma("unroll") \
  for (int i_ = 0; i_ < CIN; ++i_) ACC = fmaf((F)[i_], W[i_], ACC); }

#define PROC(E) do { \
  unsigned in_ = (E) & 0x3FFFFu; \
  int kl_ = ((E) >> 18) & 3; \
  int rl_ = (int)((E) >> 20); \
  const float* f_ = feat + (size_t)in_ * CIN; \
  float acc_ = 0.f; \
  if (kl_ == 0)      DOT32(f_, w0, acc_) \
  else if (kl_ == 1) DOT32(f_, w1, acc_) \
  else               DOT32(f_, w2, acc_) \
  atomicAdd(&tile[rl_][c], acc_); \
} while (0)

__global__ __launch_bounds__(NGRP * 64) void gather_out_kernel(
    const float* __restrict__ feat,      // [N][CIN]
    const uint32_t* __restrict__ binned, // [E]
    const int* __restrict__ start,       // [NGRP*N + 1]
    const float* __restrict__ kern,      // [KVOL][CIN][COUT]
    const float* __restrict__ bias,      // [COUT]
    float* __restrict__ out,             // [N][COUT]
    int N) {
  __shared__ float tile[RB][COUT];
  const int w  = threadIdx.x >> 6;   // kgroup 0..8
  const int c  = threadIdx.x & 63;   // output channel
  const int R0 = blockIdx.x * RB;

  for (int i = threadIdx.x; i < RB * COUT; i += NGRP * 64) ((float*)tile)[i] = 0.f;

  // per-lane weight columns for this wave's 3 offsets
  float w0[CIN], w1[CIN], w2[CIN];
  {
    const float* kb = kern + (size_t)(w * KPG) * CIN * COUT + c;
#pragma unroll
    for (int i = 0; i < CIN; ++i) w0[i] = kb[i * COUT];
#pragma unroll
    for (int i = 0; i < CIN; ++i) w1[i] = kb[CIN * COUT + i * COUT];
#pragma unroll
    for (int i = 0; i < CIN; ++i) w2[i] = kb[2 * CIN * COUT + i * COUT];
  }
  __syncthreads();

  const int b0 = w * N + R0;
  const int s0 = start[b0];
  const int cnt = start[b0 + RB] - s0;   // bins globally contiguous

  for (int base = 0; base < cnt; base += 64) {
    int idx = base + c;
    unsigned ent = (idx < cnt) ? binned[s0 + idx] : 0u;
    int jn = cnt - base; if (jn > 64) jn = 64;
    int j = 0;
    for (; j + 2 <= jn; j += 2) {
      unsigned ea = (unsigned)__builtin_amdgcn_readlane((int)ent, j);
      unsigned eb = (unsigned)__builtin_amdgcn_readlane((int)ent, j + 1);
      PROC(ea);
      PROC(eb);
    }
    if (j < jn) {
      unsigned ea = (unsigned)__builtin_amdgcn_readlane((int)ent, j);
      PROC(ea);
    }
  }
  __syncthreads();

  // write tile + bias (disjoint rows -> plain stores)
  for (int i = threadIdx.x; i < RB * COUT / 4; i += NGRP * 64) {
    int r = i >> 4, q = i & 15;
    float4 v = ((float4*)tile[r])[q];
    float4 b = ((const float4*)bias)[q];
    v.x += b.x; v.y += b.y; v.z += b.z; v.w += b.w;
    ((float4*)(out + (size_t)(R0 + r) * COUT))[q] = v;
  }
}

// ---------------------------------------------------------------------------
extern "C" void kernel_launch(void* const* d_in, const int* in_sizes, int n_in,
                              void* d_out, int out_size, void* d_ws, size_t ws_size,
                              hipStream_t stream) {
  const float* feat = (const float*)d_in[0];
  const int2*  kmap = (const int2*)d_in[3];
  const float* kern = (const float*)d_in[4];
  const float* bias = (const float*)d_in[5];
  float* out = (float*)d_out;

  const int N = in_sizes[0] / CIN;          // 200000
  const int M = in_sizes[3] / (2 * KVOL);   // 100000
  const int E = KVOL * M;                   // 2.7M
  const int NB = NGRP * N;                  // 1.8M bins

  // workspace partition (all int32/uint32)
  int* count   = (int*)d_ws;                 // NB
  int* start   = count + NB;                 // NB + 1
  int* cursor  = start + NB + 1;             // NB
  int* partial = cursor + NB;                // 4096
  uint32_t* binned = (uint32_t*)(partial + 4096); // E

  const int nchunks = (NB + SCAN_CHUNK - 1) / SCAN_CHUNK;

  hipMemsetAsync(count, 0, (size_t)NB * sizeof(int), stream);

  dim3 pgrid((M + 255) / 256, KVOL);
  hipLaunchKernelGGL(hist_kernel, pgrid, dim3(256), 0, stream, kmap, count, M, N);
  hipLaunchKernelGGL(scan_reduce, dim3(nchunks), dim3(256), 0, stream, count, partial, NB);
  hipLaunchKernelGGL(scan_partials, dim3(1), dim3(64), 0, stream, partial, nchunks, start + NB);
  hipLaunchKernelGGL(scan_down, dim3(nchunks), dim3(256), 0, stream,
                     count, partial, start, cursor, NB);
  hipLaunchKernelGGL(scatter_kernel, pgrid, dim3(256), 0, stream, kmap, cursor, binned, M, N);
  hipLaunchKernelGGL(gather_out_kernel, dim3(N / RB), dim3(NGRP * 64), 0, stream,
                     feat, binned, start, kern, bias, out, N);
}